// Round 11
// baseline (238.509 us; speedup 1.0000x reference)
//
#include <hip/hip_runtime.h>
#include <math.h>

// Shapes: B=8, T=16, H=64, W=64, D=256, DK=128, TOP_K=4
// pixels N = B*H*W = 32768 (4096 per batch)
//
// Factorization: out = (sum_t attn_t * hist_t) @ (Wv@Wo)
//                score_t = (q @ (Wq@Wk^T)) . hist_t / sqrt(128)
// hist read exactly once, double-buffered in registers.
// Score path fully fp32 (top-k selection is precision-critical).
//
// R11: TLP-with-prefetch experiment. 16 px/block (As = 16.6 KB LDS),
// 4 rows/wave, same dbuf prefetch as R5/R10, __launch_bounds__(256,3)
// -> ~12 waves/CU (1.5x R5) and 2048 fine blocks that de-phase, letting
// one block's GEMM VALU hide under another's hist stream. Per-pixel
// arithmetic bit-identical to R5/R10.

// ---------------- Kernel P: M1 = Wq@Wk^T, M2 = Wv@Wo (256x256 each) -------
__global__ __launch_bounds__(256) void precompute_weights(
    const float* __restrict__ Wq, const float* __restrict__ Wk,
    const float* __restrict__ Wv, const float* __restrict__ Wo,
    float* __restrict__ M1, float* __restrict__ M2) {
  __shared__ float rowbuf[128];
  int bid = blockIdx.x, tid = threadIdx.x;
  if (bid < 256) {
    if (tid < 128) rowbuf[tid] = Wq[bid * 128 + tid];
    __syncthreads();
    const float4* Wk4 = (const float4*)Wk;
    const float4* rb4 = (const float4*)rowbuf;
    float acc = 0.f;
#pragma unroll 8
    for (int k4 = 0; k4 < 32; ++k4) {
      float4 a = rb4[k4];
      float4 b = Wk4[tid * 32 + k4];
      acc = fmaf(a.x, b.x, acc); acc = fmaf(a.y, b.y, acc);
      acc = fmaf(a.z, b.z, acc); acc = fmaf(a.w, b.w, acc);
    }
    M1[bid * 256 + tid] = acc;
  } else {
    int d = bid - 256;
    if (tid < 128) rowbuf[tid] = Wv[d * 128 + tid];
    __syncthreads();
    float acc = 0.f;
#pragma unroll 8
    for (int k = 0; k < 128; ++k)
      acc = fmaf(rowbuf[k], Wo[k * 256 + tid], acc);
    M2[d * 256 + tid] = acc;
  }
}

// ---------------- Mega-kernel: qm -> attention -> out-projection ----------
// 16 pixels/block, 4 waves, wave w owns rows {w + 4*i, i=0..3}. NO barriers.
__global__ __launch_bounds__(256, 3) void fused_all(
    const float* __restrict__ query, const float* __restrict__ hist,
    const float* __restrict__ M1, const float* __restrict__ M2,
    float* __restrict__ OUT) {
  __shared__ float As[16][260];  // per-wave 4-row slice: query->qm->hbar
  int tid = threadIdx.x;
  int l = tid & 63;   // lane
  int w = tid >> 6;   // wave
  int pix0 = blockIdx.x * 16;

  // hist geometry (float4 units)
  const float4* H4 = (const float4*)hist;
  int b = pix0 >> 12;  // 16-pixel tile never crosses a batch (4096%16==0)
  int off0 = pix0 & 4095;
  size_t hblk = ((size_t)b * 16 * 4096 + off0) * 64 + l;
  int t_mine = l & 15;
  int gbase = l & 48;  // 16-lane replica group base

  // ---- prefetch pixel row=w (first pixel) BEFORE phase 0 ----
  float4 hA[16], hB[16];
#pragma unroll
  for (int t = 0; t < 16; ++t)
    hA[t] = H4[hblk + (size_t)w * 64 + (size_t)t * 262144];

  // ---------- phase 0: own 4 rows {w+4j} of qm = query @ M1 ----------
  {
    const float4* Qb4 = (const float4*)(query + (size_t)pix0 * 256);
#pragma unroll
    for (int k = 0; k < 4; ++k)
      *(float4*)&As[w + 4 * k][4 * l] = Qb4[(size_t)(w + 4 * k) * 64 + l];
    float4 acc[4];
#pragma unroll
    for (int j = 0; j < 4; ++j) acc[j] = make_float4(0.f, 0.f, 0.f, 0.f);
    const float4* B4 = (const float4*)M1;
#pragma unroll 4
    for (int d = 0; d < 256; ++d) {
      float4 bv = B4[d * 64 + l];
#pragma unroll
      for (int j = 0; j < 4; ++j) {
        float a = As[w + 4 * j][d];  // uniform -> LDS broadcast
        acc[j].x = fmaf(a, bv.x, acc[j].x);
        acc[j].y = fmaf(a, bv.y, acc[j].y);
        acc[j].z = fmaf(a, bv.z, acc[j].z);
        acc[j].w = fmaf(a, bv.w, acc[j].w);
      }
    }
    // all reads of own query rows done (program order) -> overwrite with qm
#pragma unroll
    for (int j = 0; j < 4; ++j)
      *(float4*)&As[w + 4 * j][4 * l] = acc[j];
  }

  // ---------- phase 1: stream hist, score, top-4, softmax, hbar ----------
#define ATTN_STEP(HC, HN, IT, DOPRE)                                        \
  {                                                                         \
    int row = w + 4 * (IT);                                                 \
    size_t nb = hblk + (size_t)(row + 4) * 64;                              \
    if (DOPRE) { /* first half of next pixel's loads */                     \
      _Pragma("unroll") for (int t = 0; t < 8; ++t)                         \
          HN[t] = H4[nb + (size_t)t * 262144];                              \
    }                                                                       \
    float4 q = *(const float4*)&As[row][4 * l];                             \
    float part[16];                                                         \
    _Pragma("unroll") for (int t = 0; t < 8; ++t) {                         \
      float s = HC[t].x * q.x;                                              \
      s = fmaf(HC[t].y, q.y, s);                                            \
      s = fmaf(HC[t].z, q.z, s);                                            \
      s = fmaf(HC[t].w, q.w, s);                                            \
      part[t] = s;                                                          \
    }                                                                       \
    if (DOPRE) { /* second half of next pixel's loads */                    \
      _Pragma("unroll") for (int t = 8; t < 16; ++t)                        \
          HN[t] = H4[nb + (size_t)t * 262144];                              \
    }                                                                       \
    _Pragma("unroll") for (int t = 8; t < 16; ++t) {                        \
      float s = HC[t].x * q.x;                                              \
      s = fmaf(HC[t].y, q.y, s);                                            \
      s = fmaf(HC[t].z, q.z, s);                                            \
      s = fmaf(HC[t].w, q.w, s);                                            \
      part[t] = s;                                                          \
    }                                                                       \
    _Pragma("unroll") for (int st = 0; st < 4; ++st) {                      \
      bool hi = (l >> st) & 1;                                              \
      int nt = 8 >> st;                                                     \
      _Pragma("unroll") for (int i = 0; i < nt; ++i) {                      \
        float mine = hi ? part[2 * i + 1] : part[2 * i];                    \
        float oth = hi ? part[2 * i] : part[2 * i + 1];                     \
        part[i] = mine + __shfl_xor(oth, 1 << st);                          \
      }                                                                     \
    }                                                                       \
    float v = part[0];                                                      \
    v += __shfl_xor(v, 16);                                                 \
    v += __shfl_xor(v, 32);                                                 \
    float sc = v * 0.08838834764831845f; /* 1/sqrt(128); t = l&15 */        \
    int rank = 0; /* exact lax.top_k: lowest-index tie-break */             \
    _Pragma("unroll") for (int k = 1; k < 16; ++k) {                        \
      int ot = (t_mine + k) & 15;                                           \
      float o = __shfl(sc, gbase | ot);                                     \
      rank += (o > sc) || (o == sc && ot < t_mine);                         \
    }                                                                       \
    bool chosen = rank < 4;                                                 \
    float earg = sc + (float)(16 - t_mine) * -0.05129329438755058f;         \
    float ex = chosen ? expf(earg) : 0.0f;                                  \
    float Z = ex;                                                           \
    Z += __shfl_xor(Z, 1);                                                  \
    Z += __shfl_xor(Z, 2);                                                  \
    Z += __shfl_xor(Z, 4);                                                  \
    Z += __shfl_xor(Z, 8);                                                  \
    float attn = ex / Z;                                                    \
    float4 hb = make_float4(0.f, 0.f, 0.f, 0.f);                            \
    _Pragma("unroll") for (int t = 0; t < 16; ++t) {                        \
      float a = __shfl(attn, gbase | t); /* uniform in value across wave */ \
      if (a != 0.0f) {                                                      \
        hb.x = fmaf(a, HC[t].x, hb.x);                                      \
        hb.y = fmaf(a, HC[t].y, hb.y);                                      \
        hb.z = fmaf(a, HC[t].z, hb.z);                                      \
        hb.w = fmaf(a, HC[t].w, hb.w);                                      \
      }                                                                     \
    }                                                                       \
    *(float4*)&As[row][4 * l] = hb; /* q already in reg; row wave-owned */  \
  }

  ATTN_STEP(hA, hB, 0, true)
  ATTN_STEP(hB, hA, 1, true)
  ATTN_STEP(hA, hB, 2, true)
  ATTN_STEP(hB, hA, 3, false)
#undef ATTN_STEP

  // ---------- phase 2: own 4 rows {w+4j} of OUT = As(hbar) @ M2 ----------
  {
    float4 acc[4];
#pragma unroll
    for (int j = 0; j < 4; ++j) acc[j] = make_float4(0.f, 0.f, 0.f, 0.f);
    const float4* B4 = (const float4*)M2;
#pragma unroll 4
    for (int d = 0; d < 256; ++d) {
      float4 bv = B4[d * 64 + l];
#pragma unroll
      for (int j = 0; j < 4; ++j) {
        float a = As[w + 4 * j][d];  // uniform -> LDS broadcast
        acc[j].x = fmaf(a, bv.x, acc[j].x);
        acc[j].y = fmaf(a, bv.y, acc[j].y);
        acc[j].z = fmaf(a, bv.z, acc[j].z);
        acc[j].w = fmaf(a, bv.w, acc[j].w);
      }
    }
    float4* C4 = (float4*)(OUT + (size_t)pix0 * 256);
#pragma unroll
    for (int j = 0; j < 4; ++j)
      C4[(w + 4 * j) * 64 + l] = acc[j];
  }
}

// --------------------------------------------------------------------------
extern "C" void kernel_launch(void* const* d_in, const int* in_sizes, int n_in,
                              void* d_out, int out_size, void* d_ws,
                              size_t ws_size, hipStream_t stream) {
  const float* query = (const float*)d_in[0];  // [8,64,64,256]
  const float* hist = (const float*)d_in[1];   // [8,16,64,64,256]
  const float* Wq = (const float*)d_in[2];     // [256,128]
  const float* Wk = (const float*)d_in[3];     // [256,128]
  const float* Wv = (const float*)d_in[4];     // [256,128]
  const float* Wo = (const float*)d_in[5];     // [128,256]
  float* out = (float*)d_out;                  // [32768,256]

  float* ws = (float*)d_ws;
  float* M1 = ws;          // 65536 floats
  float* M2 = ws + 65536;  // 65536 floats

  precompute_weights<<<512, 256, 0, stream>>>(Wq, Wk, Wv, Wo, M1, M2);
  fused_all<<<2048, 256, 0, stream>>>(query, hist, M1, M2, out);
}

// Round 12
// 215.014 us; speedup vs baseline: 1.1093x; 1.1093x over previous
//
#include <hip/hip_runtime.h>
#include <math.h>

// Shapes: B=8, T=16, H=64, W=64, D=256, DK=128, TOP_K=4
// pixels N = B*H*W = 32768 (4096 per batch)
//
// Factorization: out = (sum_t attn_t * hist_t) @ (Wv@Wo)
//                score_t = (q @ (Wq@Wk^T)) . hist_t / sqrt(128)
// hist read exactly once, double-buffered in registers.
// Score path fully fp32 (top-k selection is precision-critical).
//
// R12 = R10 champion retiled: 32 px/block (As = 33.3 KB -> LDS allows 4
// blocks/CU; VGPR ~170 -> 3 blocks/CU, 12 waves/CU), grid 1024 so blocks
// turn over and one block's GEMM VALU overlaps another block's hist
// stream. Explicit dbuf + (256,2) kept (R9 showed the compiler SINKS
// batched loads to save VGPR without the explicit two-buffer structure).
// Wave w owns rows {w+4i}; per-pixel arithmetic bit-identical to R10.

// ---------------- Kernel P: M1 = Wq@Wk^T, M2 = Wv@Wo (256x256 each) -------
__global__ __launch_bounds__(256) void precompute_weights(
    const float* __restrict__ Wq, const float* __restrict__ Wk,
    const float* __restrict__ Wv, const float* __restrict__ Wo,
    float* __restrict__ M1, float* __restrict__ M2) {
  __shared__ float rowbuf[128];
  int bid = blockIdx.x, tid = threadIdx.x;
  if (bid < 256) {
    if (tid < 128) rowbuf[tid] = Wq[bid * 128 + tid];
    __syncthreads();
    const float4* Wk4 = (const float4*)Wk;
    const float4* rb4 = (const float4*)rowbuf;
    float acc = 0.f;
#pragma unroll 8
    for (int k4 = 0; k4 < 32; ++k4) {
      float4 a = rb4[k4];
      float4 b = Wk4[tid * 32 + k4];
      acc = fmaf(a.x, b.x, acc); acc = fmaf(a.y, b.y, acc);
      acc = fmaf(a.z, b.z, acc); acc = fmaf(a.w, b.w, acc);
    }
    M1[bid * 256 + tid] = acc;
  } else {
    int d = bid - 256;
    if (tid < 128) rowbuf[tid] = Wv[d * 128 + tid];
    __syncthreads();
    float acc = 0.f;
#pragma unroll 8
    for (int k = 0; k < 128; ++k)
      acc = fmaf(rowbuf[k], Wo[k * 256 + tid], acc);
    M2[d * 256 + tid] = acc;
  }
}

// ---------------- Mega-kernel: qm -> attention -> out-projection ----------
// 32 pixels/block, 4 waves, wave w owns rows {w + 4*i, i=0..7}. NO barriers.
__global__ __launch_bounds__(256, 2) void fused_all(
    const float* __restrict__ query, const float* __restrict__ hist,
    const float* __restrict__ M1, const float* __restrict__ M2,
    float* __restrict__ OUT) {
  __shared__ float As[32][260];  // per-wave 8-row slice: query->qm->hbar
  int tid = threadIdx.x;
  int l = tid & 63;   // lane
  int w = tid >> 6;   // wave
  int pix0 = blockIdx.x * 32;

  // hist geometry (float4 units)
  const float4* H4 = (const float4*)hist;
  int b = pix0 >> 12;  // 32-pixel tile never crosses a batch (4096%32==0)
  int off0 = pix0 & 4095;
  size_t hblk = ((size_t)b * 16 * 4096 + off0) * 64 + l;
  int t_mine = l & 15;
  int gbase = l & 48;  // 16-lane replica group base

  // ---------- phase 0: own 8 rows {w+4j} of qm = query @ M1 ----------
  {
    const float4* Qb4 = (const float4*)(query + (size_t)pix0 * 256);
#pragma unroll
    for (int k = 0; k < 8; ++k)
      *(float4*)&As[w + 4 * k][4 * l] = Qb4[(size_t)(w + 4 * k) * 64 + l];
    float4 acc[8];
#pragma unroll
    for (int j = 0; j < 8; ++j) acc[j] = make_float4(0.f, 0.f, 0.f, 0.f);
    const float4* B4 = (const float4*)M1;
#pragma unroll 4
    for (int d = 0; d < 256; ++d) {
      float4 bv = B4[d * 64 + l];
#pragma unroll
      for (int j = 0; j < 8; ++j) {
        float a = As[w + 4 * j][d];  // uniform -> LDS broadcast
        acc[j].x = fmaf(a, bv.x, acc[j].x);
        acc[j].y = fmaf(a, bv.y, acc[j].y);
        acc[j].z = fmaf(a, bv.z, acc[j].z);
        acc[j].w = fmaf(a, bv.w, acc[j].w);
      }
    }
    // all reads of own query rows done (program order) -> overwrite with qm
#pragma unroll
    for (int j = 0; j < 8; ++j)
      *(float4*)&As[w + 4 * j][4 * l] = acc[j];
  }

  // ---------- phase 1: stream hist, score, top-4, softmax, hbar ----------
  float4 hA[16], hB[16];
#pragma unroll
  for (int t = 0; t < 16; ++t)  // pixel row = w
    hA[t] = H4[hblk + (size_t)w * 64 + (size_t)t * 262144];

#define ATTN_STEP(HC, HN, IT, DOPRE)                                        \
  {                                                                         \
    int row = w + 4 * (IT);                                                 \
    if (DOPRE) { /* prefetch next pixel (row+4) into HN */                  \
      size_t nb = hblk + (size_t)(row + 4) * 64;                            \
      _Pragma("unroll") for (int t = 0; t < 16; ++t)                        \
          HN[t] = H4[nb + (size_t)t * 262144];                              \
    }                                                                       \
    float4 q = *(const float4*)&As[row][4 * l];                             \
    float part[16];                                                         \
    _Pragma("unroll") for (int t = 0; t < 16; ++t) {                        \
      float s = HC[t].x * q.x;                                              \
      s = fmaf(HC[t].y, q.y, s);                                            \
      s = fmaf(HC[t].z, q.z, s);                                            \
      s = fmaf(HC[t].w, q.w, s);                                            \
      part[t] = s;                                                          \
    }                                                                       \
    _Pragma("unroll") for (int st = 0; st < 4; ++st) {                      \
      bool hi = (l >> st) & 1;                                              \
      int nt = 8 >> st;                                                     \
      _Pragma("unroll") for (int i = 0; i < nt; ++i) {                      \
        float mine = hi ? part[2 * i + 1] : part[2 * i];                    \
        float oth = hi ? part[2 * i] : part[2 * i + 1];                     \
        part[i] = mine + __shfl_xor(oth, 1 << st);                          \
      }                                                                     \
    }                                                                       \
    float v = part[0];                                                      \
    v += __shfl_xor(v, 16);                                                 \
    v += __shfl_xor(v, 32);                                                 \
    float sc = v * 0.08838834764831845f; /* 1/sqrt(128); t = l&15 */        \
    int rank = 0; /* exact lax.top_k: lowest-index tie-break */             \
    _Pragma("unroll") for (int k = 1; k < 16; ++k) {                        \
      int ot = (t_mine + k) & 15;                                           \
      float o = __shfl(sc, gbase | ot);                                     \
      rank += (o > sc) || (o == sc && ot < t_mine);                         \
    }                                                                       \
    bool chosen = rank < 4;                                                 \
    float earg = sc + (float)(16 - t_mine) * -0.05129329438755058f;         \
    float ex = chosen ? expf(earg) : 0.0f;                                  \
    float Z = ex;                                                           \
    Z += __shfl_xor(Z, 1);                                                  \
    Z += __shfl_xor(Z, 2);                                                  \
    Z += __shfl_xor(Z, 4);                                                  \
    Z += __shfl_xor(Z, 8);                                                  \
    float attn = ex / Z;                                                    \
    float4 hb = make_float4(0.f, 0.f, 0.f, 0.f);                            \
    _Pragma("unroll") for (int t = 0; t < 16; ++t) {                        \
      float a = __shfl(attn, gbase | t); /* uniform in value across wave */ \
      if (a != 0.0f) {                                                      \
        hb.x = fmaf(a, HC[t].x, hb.x);                                      \
        hb.y = fmaf(a, HC[t].y, hb.y);                                      \
        hb.z = fmaf(a, HC[t].z, hb.z);                                      \
        hb.w = fmaf(a, HC[t].w, hb.w);                                      \
      }                                                                     \
    }                                                                       \
    *(float4*)&As[row][4 * l] = hb; /* q already in reg; row wave-owned */  \
  }

  for (int it2 = 0; it2 < 4; ++it2) {
    ATTN_STEP(hA, hB, 2 * it2, true);
    ATTN_STEP(hB, hA, 2 * it2 + 1, it2 < 3);
  }
#undef ATTN_STEP

  // ---------- phase 2: own 8 rows {w+4j} of OUT = As(hbar) @ M2 ----------
  {
    float4 acc[8];
#pragma unroll
    for (int j = 0; j < 8; ++j) acc[j] = make_float4(0.f, 0.f, 0.f, 0.f);
    const float4* B4 = (const float4*)M2;
#pragma unroll 4
    for (int d = 0; d < 256; ++d) {
      float4 bv = B4[d * 64 + l];
#pragma unroll
      for (int j = 0; j < 8; ++j) {
        float a = As[w + 4 * j][d];  // uniform -> LDS broadcast
        acc[j].x = fmaf(a, bv.x, acc[j].x);
        acc[j].y = fmaf(a, bv.y, acc[j].y);
        acc[j].z = fmaf(a, bv.z, acc[j].z);
        acc[j].w = fmaf(a, bv.w, acc[j].w);
      }
    }
    float4* C4 = (float4*)(OUT + (size_t)pix0 * 256);
#pragma unroll
    for (int j = 0; j < 8; ++j)
      C4[(w + 4 * j) * 64 + l] = acc[j];
  }
}

// --------------------------------------------------------------------------
extern "C" void kernel_launch(void* const* d_in, const int* in_sizes, int n_in,
                              void* d_out, int out_size, void* d_ws,
                              size_t ws_size, hipStream_t stream) {
  const float* query = (const float*)d_in[0];  // [8,64,64,256]
  const float* hist = (const float*)d_in[1];   // [8,16,64,64,256]
  const float* Wq = (const float*)d_in[2];     // [256,128]
  const float* Wk = (const float*)d_in[3];     // [256,128]
  const float* Wv = (const float*)d_in[4];     // [256,128]
  const float* Wo = (const float*)d_in[5];     // [128,256]
  float* out = (float*)d_out;                  // [32768,256]

  float* ws = (float*)d_ws;
  float* M1 = ws;          // 65536 floats
  float* M2 = ws + 65536;  // 65536 floats

  precompute_weights<<<512, 256, 0, stream>>>(Wq, Wk, Wv, Wo, M1, M2);
  fused_all<<<1024, 256, 0, stream>>>(query, hist, M1, M2, out);
}

// Round 13
// 170.709 us; speedup vs baseline: 1.3972x; 1.2595x over previous
//
#include <hip/hip_runtime.h>
#include <math.h>

// Shapes: B=8, T=16, H=64, W=64, D=256, DK=128, TOP_K=4
// pixels N = B*H*W = 32768 (4096 per batch)
//
// Factorization: out = (sum_t attn_t * hist_t) @ (Wv@Wo)
//                score_t = (q @ (Wq@Wk^T)) . hist_t / sqrt(128)
// hist read exactly once, double-buffered in registers.
// Score path fully fp32 (top-k selection is precision-critical).
//
// R13 = R10 champion (64px/block, rows {w+4i}, grid 512, dbuf, (256,2))
// with phase 2 (out-projection) moved to bf16 MFMA (16x16x32). The
// projection is not top-k-critical; bf16 rounding adds ~1e-2 worst-case
// (threshold 7.7e-2). Saves ~27us of serial fp32 VALU. M2 is packed to
// bf16 in B-fragment order (M2F) by the precompute kernel.

typedef __attribute__((ext_vector_type(8))) short bf16x8;
typedef __attribute__((ext_vector_type(4))) float f32x4;

__device__ inline unsigned short f2bf(float f) {
  union { float f; unsigned u; } v; v.f = f;
  unsigned r = (v.u + 0x7FFF + ((v.u >> 16) & 1)) >> 16;  // RNE
  return (unsigned short)r;
}

// ---------------- Kernel P: M1 = Wq@Wk^T, M2F = bf16-frag(Wv@Wo) ----------
__global__ __launch_bounds__(256) void precompute_weights(
    const float* __restrict__ Wq, const float* __restrict__ Wk,
    const float* __restrict__ Wv, const float* __restrict__ Wo,
    float* __restrict__ M1, unsigned short* __restrict__ M2F) {
  __shared__ float rowbuf[128];
  int bid = blockIdx.x, tid = threadIdx.x;
  if (bid < 256) {
    if (tid < 128) rowbuf[tid] = Wq[bid * 128 + tid];
    __syncthreads();
    const float4* Wk4 = (const float4*)Wk;
    const float4* rb4 = (const float4*)rowbuf;
    float acc = 0.f;
#pragma unroll 8
    for (int k4 = 0; k4 < 32; ++k4) {
      float4 a = rb4[k4];
      float4 b = Wk4[tid * 32 + k4];
      acc = fmaf(a.x, b.x, acc); acc = fmaf(a.y, b.y, acc);
      acc = fmaf(a.z, b.z, acc); acc = fmaf(a.w, b.w, acc);
    }
    M1[bid * 256 + tid] = acc;
  } else {
    int k = bid - 256;  // M2 row index
    if (tid < 128) rowbuf[tid] = Wv[k * 128 + tid];
    __syncthreads();
    float acc = 0.f;
#pragma unroll 8
    for (int kk = 0; kk < 128; ++kk)
      acc = fmaf(rowbuf[kk], Wo[kk * 256 + tid], acc);
    // scatter into MFMA B-fragment layout:
    // frag(ct,kt): lane l holds B[kt*32 + (l>>4)*8 + i][ct*16 + (l&15)]
    int c = tid;
    int ct = c >> 4, kt = k >> 5, lh = (k >> 3) & 3, i = k & 7, lm = c & 15;
    M2F[(size_t)(((ct * 8 + kt) * 64 + lh * 16 + lm) * 8 + i)] = f2bf(acc);
  }
}

// ---------------- Mega-kernel: qm -> attention -> out-projection ----------
// 64 pixels/block, 4 waves, wave w owns rows {w + 4*i}. NO barriers.
__global__ __launch_bounds__(256, 2) void fused_all(
    const float* __restrict__ query, const float* __restrict__ hist,
    const float* __restrict__ M1, const unsigned short* __restrict__ M2F,
    float* __restrict__ OUT) {
  __shared__ float As[64][260];  // per-wave 16-row slice: query->qm->hbar
  int tid = threadIdx.x;
  int l = tid & 63;   // lane
  int w = tid >> 6;   // wave
  int pix0 = blockIdx.x * 64;

  // hist geometry (float4 units)
  const float4* H4 = (const float4*)hist;
  int b = pix0 >> 12;  // 64-pixel tile never crosses a batch
  int off0 = pix0 & 4095;
  size_t hblk = ((size_t)b * 16 * 4096 + off0) * 64 + l;
  int t_mine = l & 15;
  int gbase = l & 48;  // 16-lane replica group base

  // ---------- phase 0: own 16 rows {w+4j} of qm = query @ M1 (fp32) -------
  {
    const float4* Qb4 = (const float4*)(query + (size_t)pix0 * 256);
#pragma unroll
    for (int k = 0; k < 16; ++k)
      *(float4*)&As[w + 4 * k][4 * l] = Qb4[(size_t)(w + 4 * k) * 64 + l];
    float4 acc[16];
#pragma unroll
    for (int j = 0; j < 16; ++j) acc[j] = make_float4(0.f, 0.f, 0.f, 0.f);
    const float4* B4 = (const float4*)M1;
#pragma unroll 4
    for (int d = 0; d < 256; ++d) {
      float4 bv = B4[d * 64 + l];
#pragma unroll
      for (int j = 0; j < 16; ++j) {
        float a = As[w + 4 * j][d];  // uniform -> LDS broadcast
        acc[j].x = fmaf(a, bv.x, acc[j].x);
        acc[j].y = fmaf(a, bv.y, acc[j].y);
        acc[j].z = fmaf(a, bv.z, acc[j].z);
        acc[j].w = fmaf(a, bv.w, acc[j].w);
      }
    }
    // all reads of own query rows done (program order) -> overwrite with qm
#pragma unroll
    for (int j = 0; j < 16; ++j)
      *(float4*)&As[w + 4 * j][4 * l] = acc[j];
  }

  // ---------- phase 1: stream hist, score, top-4, softmax, hbar ----------
  float4 hA[16], hB[16];
#pragma unroll
  for (int t = 0; t < 16; ++t)  // pixel row = w
    hA[t] = H4[hblk + (size_t)w * 64 + (size_t)t * 262144];

#define ATTN_STEP(HC, HN, IT, DOPRE)                                        \
  {                                                                         \
    int row = w + 4 * (IT);                                                 \
    if (DOPRE) { /* prefetch next pixel (row+4) into HN */                  \
      size_t nb = hblk + (size_t)(row + 4) * 64;                            \
      _Pragma("unroll") for (int t = 0; t < 16; ++t)                        \
          HN[t] = H4[nb + (size_t)t * 262144];                              \
    }                                                                       \
    float4 q = *(const float4*)&As[row][4 * l];                             \
    float part[16];                                                         \
    _Pragma("unroll") for (int t = 0; t < 16; ++t) {                        \
      float s = HC[t].x * q.x;                                              \
      s = fmaf(HC[t].y, q.y, s);                                            \
      s = fmaf(HC[t].z, q.z, s);                                            \
      s = fmaf(HC[t].w, q.w, s);                                            \
      part[t] = s;                                                          \
    }                                                                       \
    _Pragma("unroll") for (int st = 0; st < 4; ++st) {                      \
      bool hi = (l >> st) & 1;                                              \
      int nt = 8 >> st;                                                     \
      _Pragma("unroll") for (int i = 0; i < nt; ++i) {                      \
        float mine = hi ? part[2 * i + 1] : part[2 * i];                    \
        float oth = hi ? part[2 * i] : part[2 * i + 1];                     \
        part[i] = mine + __shfl_xor(oth, 1 << st);                          \
      }                                                                     \
    }                                                                       \
    float v = part[0];                                                      \
    v += __shfl_xor(v, 16);                                                 \
    v += __shfl_xor(v, 32);                                                 \
    float sc = v * 0.08838834764831845f; /* 1/sqrt(128); t = l&15 */        \
    int rank = 0; /* exact lax.top_k: lowest-index tie-break */             \
    _Pragma("unroll") for (int k = 1; k < 16; ++k) {                        \
      int ot = (t_mine + k) & 15;                                           \
      float o = __shfl(sc, gbase | ot);                                     \
      rank += (o > sc) || (o == sc && ot < t_mine);                         \
    }                                                                       \
    bool chosen = rank < 4;                                                 \
    float earg = sc + (float)(16 - t_mine) * -0.05129329438755058f;         \
    float ex = chosen ? expf(earg) : 0.0f;                                  \
    float Z = ex;                                                           \
    Z += __shfl_xor(Z, 1);                                                  \
    Z += __shfl_xor(Z, 2);                                                  \
    Z += __shfl_xor(Z, 4);                                                  \
    Z += __shfl_xor(Z, 8);                                                  \
    float attn = ex / Z;                                                    \
    float4 hb = make_float4(0.f, 0.f, 0.f, 0.f);                            \
    _Pragma("unroll") for (int t = 0; t < 16; ++t) {                        \
      float a = __shfl(attn, gbase | t); /* uniform in value across wave */ \
      if (a != 0.0f) {                                                      \
        hb.x = fmaf(a, HC[t].x, hb.x);                                      \
        hb.y = fmaf(a, HC[t].y, hb.y);                                      \
        hb.z = fmaf(a, HC[t].z, hb.z);                                      \
        hb.w = fmaf(a, HC[t].w, hb.w);                                      \
      }                                                                     \
    }                                                                       \
    *(float4*)&As[row][4 * l] = hb; /* q already in reg; row wave-owned */  \
  }

  for (int it2 = 0; it2 < 8; ++it2) {
    ATTN_STEP(hA, hB, 2 * it2, true);
    ATTN_STEP(hB, hA, 2 * it2 + 1, it2 < 7);
  }
#undef ATTN_STEP

  // ---------- phase 2: OUT rows {w+4i} = As(hbar) @ M2  via bf16 MFMA -----
  // Per wave: 8 k-tiles x 16 col-tiles of mfma_f32_16x16x32_bf16.
  // A-frag: lane l holds hbar[logical row w+4*(l&15)][kt*32+(l>>4)*8+i].
  // B-frag: pre-packed M2F, one coalesced 16B load per lane per (ct,kt).
  // C/D: col = ct*16 + (l&15), logical row = w + 4*((l>>4)*4 + j).
  {
    int lm = l & 15, lh = l >> 4;
    const bf16x8* B8 = (const bf16x8*)M2F;
    f32x4 acc[16];
#pragma unroll
    for (int ct = 0; ct < 16; ++ct) acc[ct] = (f32x4){0.f, 0.f, 0.f, 0.f};
#pragma unroll
    for (int kt = 0; kt < 8; ++kt) {
      const float* ap = &As[w + 4 * lm][kt * 32 + lh * 8];
      float4 a0 = *(const float4*)ap;
      float4 a1 = *(const float4*)(ap + 4);
      bf16x8 afrag;
      afrag[0] = (short)f2bf(a0.x); afrag[1] = (short)f2bf(a0.y);
      afrag[2] = (short)f2bf(a0.z); afrag[3] = (short)f2bf(a0.w);
      afrag[4] = (short)f2bf(a1.x); afrag[5] = (short)f2bf(a1.y);
      afrag[6] = (short)f2bf(a1.z); afrag[7] = (short)f2bf(a1.w);
#pragma unroll
      for (int ct = 0; ct < 16; ++ct) {
        bf16x8 bfrag = B8[(ct * 8 + kt) * 64 + l];
        acc[ct] = __builtin_amdgcn_mfma_f32_16x16x32_bf16(afrag, bfrag,
                                                          acc[ct], 0, 0, 0);
      }
    }
    float* outp = OUT + (size_t)pix0 * 256;
#pragma unroll
    for (int ct = 0; ct < 16; ++ct) {
#pragma unroll
      for (int j = 0; j < 4; ++j)
        outp[(size_t)(w + 4 * (lh * 4 + j)) * 256 + ct * 16 + lm] =
            acc[ct][j];
    }
  }
}

// --------------------------------------------------------------------------
extern "C" void kernel_launch(void* const* d_in, const int* in_sizes, int n_in,
                              void* d_out, int out_size, void* d_ws,
                              size_t ws_size, hipStream_t stream) {
  const float* query = (const float*)d_in[0];  // [8,64,64,256]
  const float* hist = (const float*)d_in[1];   // [8,16,64,64,256]
  const float* Wq = (const float*)d_in[2];     // [256,128]
  const float* Wk = (const float*)d_in[3];     // [256,128]
  const float* Wv = (const float*)d_in[4];     // [256,128]
  const float* Wo = (const float*)d_in[5];     // [128,256]
  float* out = (float*)d_out;                  // [32768,256]

  float* ws = (float*)d_ws;
  float* M1 = ws;  // 65536 floats
  unsigned short* M2F = (unsigned short*)(ws + 65536);  // 65536 bf16 (frag order)

  precompute_weights<<<512, 256, 0, stream>>>(Wq, Wk, Wv, Wo, M1, M2F);
  fused_all<<<512, 256, 0, stream>>>(query, hist, M1, M2F, out);
}